// Round 2
// baseline (298.678 us; speedup 1.0000x reference)
//
#include <hip/hip_runtime.h>
#include <hip/hip_bf16.h>

#define D 256
#define DH 128
#define NB 8   // nodes per wave in fallback score kernel

typedef __attribute__((ext_vector_type(8))) short short8;
typedef __attribute__((ext_vector_type(4))) float floatx4;
typedef __attribute__((ext_vector_type(4))) unsigned int uintx4;

// ---------------------------------------------------------------------------
__device__ __forceinline__ int eload(const void* p, long long i, int is64) {
    if (is64) return (int)((const long long*)p)[i];
    return ((const int*)p)[i];
}

// fp32 bits -> bf16 (RNE), packed pair
__device__ __forceinline__ unsigned pack_bf16(unsigned a, unsigned b) {
    unsigned ra = (a + 0x7fffu + ((a >> 16) & 1u)) >> 16;
    unsigned rb = (b + 0x7fffu + ((b >> 16) & 1u)) & 0xffff0000u;
    return ra | rb;
}

__device__ __forceinline__ float4 unpack_bf16x4(uint2 v) {
    float4 r;
    r.x = __uint_as_float(v.x << 16);
    r.y = __uint_as_float(v.x & 0xffff0000u);
    r.z = __uint_as_float(v.y << 16);
    r.w = __uint_as_float(v.y & 0xffff0000u);
    return r;
}

// ---------------------------------------------------------------------------
// Prep: blocks 0..15 pack W1 into bf16 B-fragment order; block 16 zeroes the
// flag then detects whether edge_index is int64; blocks >= 17 zero the cursor
// array AND fill the cols buckets with 0xFFFF sentinels (agg never reads
// cursor -> saves ~25MB of 64B-line L2 fills there).
__global__ __launch_bounds__(256) void prep_kernel(const float* __restrict__ W1,
                                                   uint4* __restrict__ Bp,
                                                   const int* __restrict__ ei,
                                                   int* __restrict__ flag, int E,
                                                   int* __restrict__ cursor,
                                                   unsigned short* __restrict__ cols,
                                                   int cap, int N, int pad) {
    if (blockIdx.x >= 17) {
        int stride = (gridDim.x - 17) * 256;
        int tid0 = (blockIdx.x - 17) * 256 + threadIdx.x;
        // zero cursors
        int total4 = (N * pad) >> 2;
        uint4* c4 = (uint4*)cursor;
        uint4 z = make_uint4(0u, 0u, 0u, 0u);
        for (int i = tid0; i < total4; i += stride) c4[i] = z;
        // sentinel-fill cols
        int colQ = (N * cap) >> 3;          // uint4 count (8 u16 each)
        uint4* q4 = (uint4*)cols;
        uint4 f = make_uint4(~0u, ~0u, ~0u, ~0u);
        for (int i = tid0; i < colQ; i += stride) q4[i] = f;
        if (blockIdx.x == 17 && threadIdx.x == 0) {
            for (int i = total4 * 4; i < N * pad; ++i) cursor[i] = 0;
            for (int i = colQ * 8; i < N * cap; ++i) cols[i] = 0xffffu;
        }
        return;
    }
    if (blockIdx.x == 16) {
        int tid = threadIdx.x;
        if (tid == 0) *flag = 0;
        __syncthreads();
        int limit = min(E, 4096);
        int v = 0;
        for (int i = tid; i < limit; i += 256) v |= ei[2 * i + 1];
#pragma unroll
        for (int off = 32; off > 0; off >>= 1) v |= __shfl_down(v, off, 64);
        if ((tid & 63) == 0) atomicOr(flag, v);
        return;
    }
    int t = blockIdx.x * 256 + threadIdx.x;     // 0..4095
    int lane = t & 63;
    int kt = (t >> 6) & 7;
    int nt = t >> 9;
    int col = nt * 16 + (lane & 15);
    int k0 = kt * 32 + (lane >> 4) * 8;
    unsigned v[8];
#pragma unroll
    for (int j = 0; j < 8; ++j) v[j] = __float_as_uint(W1[(k0 + j) * DH + col]);
    uint4 o;
    o.x = pack_bf16(v[0], v[1]);
    o.y = pack_bf16(v[2], v[3]);
    o.z = pack_bf16(v[4], v[5]);
    o.w = pack_bf16(v[6], v[7]);
    Bp[t] = o;
}

// ---------------------------------------------------------------------------
// FUSED dispatch, NO LDS (occupancy: was 32KB -> 5 blk/CU capping the
// latency-bound scatter blocks at 31% occ; now 8 blk/CU by VGPR only).
// Blocks [0, SB): (a) cast x -> xb in XCD-SLICED layout
//   xb[slice][node][slot]: slice = dim>>5 (8 slices of 32 dims, 64B rows,
//   3.2MB/slice -> each slice fits one XCD's 4MB L2 for the agg gather),
// (b) per-node MFMA score, A-fragments read back from global xb (same-L2
//   hits: this block wrote those lines).
// Blocks [SB, ...): edge scatter into sentinel-initialized u16 buckets.
__global__ __launch_bounds__(256) void score_scatter_kernel(
        const float* __restrict__ x, const uint4* __restrict__ Bp,
        const float* __restrict__ b1, const float* __restrict__ W2,
        const float* __restrict__ b2, uint2* __restrict__ xb,
        float* __restrict__ s,
        const void* __restrict__ ep, const int* __restrict__ flag,
        int* __restrict__ cursor, unsigned short* __restrict__ cols,
        int cap, int pad, int Npad, int N, int E, int SB) {
    if ((int)blockIdx.x >= SB) {
        // ---- scatter part: 8 edges per thread
        int is64 = (*flag == 0);
        int base = (blockIdx.x - SB) * 2048 + threadIdx.x;
        int r[8], c[8];
        bool vld[8];
#pragma unroll
        for (int j = 0; j < 8; ++j) {
            int e = base + j * 256;
            vld[j] = (e < E);
            if (vld[j]) {
                r[j] = eload(ep, e, is64);
                c[j] = eload(ep, (long long)E + e, is64);
            }
        }
#pragma unroll
        for (int j = 0; j < 8; ++j) {
            if (vld[j]) {
                int p = atomicAdd(&cursor[r[j] * pad], 1);
                if (p < cap)
                    __builtin_nontemporal_store((unsigned short)c[j],
                                                &cols[(size_t)r[j] * cap + p]);
            }
        }
        return;
    }

    // ---- score part
    int tid = threadIdx.x;
    int blk = blockIdx.x;
    long long n64 = (long long)N * 64;
    int npad8 = Npad * 8;   // uint2 per slice

    // phase A: coalesced cast of this block's 64 rows into sliced xb
    long long gbase = (long long)blk * 4096 + tid;
#pragma unroll
    for (int i = 0; i < 16; ++i) {
        long long g = gbase + i * 256;
        int idx = i * 256 + tid;
        if (g < n64) {
            uint4 fv = ((const uint4*)x)[g];
            uint2 o;
            o.x = pack_bf16(fv.x, fv.y);
            o.y = pack_bf16(fv.z, fv.w);
            int row = idx >> 6, cc = idx & 63;      // cc = uint2 slot (4 dims)
            int nodeid = blk * 64 + row;
            xb[(size_t)(cc >> 3) * npad8 + (size_t)nodeid * 8 + (cc & 7)] = o;
        }
    }
    __syncthreads();   // drains vmcnt -> writes visible in this CU's L2

    // phase B: MFMA score for this wave's 16 rows, A-fragments from global xb
    int lane = tid & 63;
    int wid = tid >> 6;
    int quad = lane >> 4;
    int rbase = blk * 64 + wid * 16;
    int lnode = rbase + (lane & 15);

    short8 afrag[8];
#pragma unroll
    for (int kt = 0; kt < 8; ++kt)
        afrag[kt] = *(const short8*)&xb[(size_t)kt * npad8 + (size_t)lnode * 8 + quad * 2];

    const short8* Bs = (const short8*)Bp;
    float z0 = 0.f, z1 = 0.f, z2 = 0.f, z3 = 0.f;
#pragma unroll
    for (int nt = 0; nt < 8; ++nt) {
        floatx4 acc = {0.f, 0.f, 0.f, 0.f};
#pragma unroll
        for (int kt = 0; kt < 8; ++kt) {
            short8 b = Bs[(nt * 8 + kt) * 64 + lane];
            acc = __builtin_amdgcn_mfma_f32_16x16x32_bf16(afrag[kt], b, acc, 0, 0, 0);
        }
        int col = nt * 16 + (lane & 15);
        float b1c = b1[col], w2c = W2[col];
        z0 += fmaxf(acc[0] + b1c, 0.f) * w2c;
        z1 += fmaxf(acc[1] + b1c, 0.f) * w2c;
        z2 += fmaxf(acc[2] + b1c, 0.f) * w2c;
        z3 += fmaxf(acc[3] + b1c, 0.f) * w2c;
    }

#pragma unroll
    for (int off = 1; off < 16; off <<= 1) {
        z0 += __shfl_xor(z0, off, 64);
        z1 += __shfl_xor(z1, off, 64);
        z2 += __shfl_xor(z2, off, 64);
        z3 += __shfl_xor(z3, off, 64);
    }
    if ((lane & 15) == 0) {
        float b2v = b2[0];
        int r = rbase + quad * 4;
        float zz[4] = {z0, z1, z2, z3};
#pragma unroll
        for (int j = 0; j < 4; ++j)
            if (r + j < N) s[r + j] = 1.f / (1.f + __expf(-(zz[j] + b2v)));
    }
}

// ---------------------------------------------------------------------------
// XCD-sliced aggregation. slice = blockIdx&7 == XCD id (round-robin dispatch)
// -> each XCD's L2 only ever gathers its own 3.2MB dim-slice of xb (fits!).
// One wave per (node, slice): lanes = 8 edge-slots x 8 dim-quads.
// cols read as one broadcast uint4 (8 edges) per chunk; sentinel 0xFFFF ends
// the bucket (cursor never read). den is recomputed per slice (cheap).
__global__ __launch_bounds__(256) void agg_slice_kernel(
        const uint2* __restrict__ xb, const float* __restrict__ s,
        const unsigned short* __restrict__ cols,
        int cap, int Npad, float4* __restrict__ out4, int N) {
    int slice = blockIdx.x & 7;
    int group = blockIdx.x >> 3;
    int wid = threadIdx.x >> 6;
    int lane = threadIdx.x & 63;
    int oct = lane >> 3;        // edge slot within chunk
    int dl  = lane & 7;         // dim quad within slice (4 dims)
    int node = group * 4 + wid;
    if (node >= N) return;

    const uint4* mc4 = (const uint4*)(cols + (size_t)node * cap);
    const uint2* xbs = xb + (size_t)slice * Npad * 8;

    float4 acc = make_float4(0.f, 0.f, 0.f, 0.f);
    float den = 0.f;
    int chunks = cap >> 3;
    uint4 cv = mc4[0];
    for (int i = 0; i < chunks; ++i) {
        if ((cv.x & 0xffffu) == 0xffffu) break;   // edge i*8 absent -> done
        uint4 cn;
        if (i + 1 < chunks) cn = mc4[i + 1];
        else cn = make_uint4(~0u, ~0u, ~0u, ~0u);
        unsigned cw = (oct & 4) ? ((oct & 2) ? cv.w : cv.z)
                                : ((oct & 2) ? cv.y : cv.x);
        unsigned col = (oct & 1) ? (cw >> 16) : (cw & 0xffffu);
        bool valid = (col != 0xffffu);
        int ci = valid ? (int)col : 0;
        float sv = s[ci];
        sv = valid ? sv : 0.f;
        uint2 v = xbs[(size_t)ci * 8 + dl];
        float4 f = unpack_bf16x4(v);
        acc.x = fmaf(f.x, sv, acc.x);
        acc.y = fmaf(f.y, sv, acc.y);
        acc.z = fmaf(f.z, sv, acc.z);
        acc.w = fmaf(f.w, sv, acc.w);
        den += sv;
        cv = cn;
    }
    // reduce across the 8 edge slots (strides 8,16,32 leave dim lanes intact)
#pragma unroll
    for (int off = 8; off < 64; off <<= 1) {
        acc.x += __shfl_xor(acc.x, off, 64);
        acc.y += __shfl_xor(acc.y, off, 64);
        acc.z += __shfl_xor(acc.z, off, 64);
        acc.w += __shfl_xor(acc.w, off, 64);
        den   += __shfl_xor(den,   off, 64);
    }
    if (oct == 0) {
        floatx4 o = {0.f, 0.f, 0.f, 0.f};
        if (den > 0.f) {
            float inv = 1.f / den;
            o.x = acc.x * inv; o.y = acc.y * inv;
            o.z = acc.z * inv; o.w = acc.w * inv;
        }
        __builtin_nontemporal_store(
            o, (floatx4*)&out4[(size_t)node * 64 + slice * 8 + dl]);
    }
}

// ---------------------------------------------------------------------------
// ------- legacy fp32 fallback path (only if workspace is tiny) -------------
__global__ __launch_bounds__(256) void detect_kernel(const int* __restrict__ ei,
                                                     int* __restrict__ flag, int E) {
    int tid = threadIdx.x;
    int limit = min(E, 4096);
    int v = 0;
    for (int i = tid; i < limit; i += 256) v |= ei[2 * i + 1];
#pragma unroll
    for (int off = 32; off > 0; off >>= 1) v |= __shfl_down(v, off, 64);
    if ((tid & 63) == 0) atomicOr(flag, v);
}

__global__ __launch_bounds__(256) void score_kernel(const float* __restrict__ x,
                                                    const float* __restrict__ W1,
                                                    const float* __restrict__ b1,
                                                    const float* __restrict__ W2,
                                                    const float* __restrict__ b2,
                                                    float* __restrict__ s, int N) {
    __shared__ __align__(16) float xs[4][NB][D];
    int lane = threadIdx.x & 63;
    int wid  = threadIdx.x >> 6;
    int base = (blockIdx.x * 4 + wid) * NB;
#pragma unroll
    for (int m = 0; m < NB; ++m) {
        int n = base + m;
        float4 v = make_float4(0.f, 0.f, 0.f, 0.f);
        if (n < N) v = ((const float4*)x)[(size_t)n * 64 + lane];
        ((float4*)&xs[wid][m][0])[lane] = v;
    }
    __syncthreads();
    float h0[NB], h1[NB];
#pragma unroll
    for (int m = 0; m < NB; ++m) { h0[m] = 0.f; h1[m] = 0.f; }
#pragma unroll 4
    for (int k = 0; k < D; ++k) {
        float w1a = W1[k * DH + lane];
        float w1b = W1[k * DH + 64 + lane];
#pragma unroll
        for (int m = 0; m < NB; ++m) {
            float xv = xs[wid][m][k];
            h0[m] = fmaf(xv, w1a, h0[m]);
            h1[m] = fmaf(xv, w1b, h1[m]);
        }
    }
    float b1a = b1[lane], b1b = b1[lane + 64];
    float w2a = W2[lane], w2b = W2[lane + 64];
    float b2v = b2[0];
#pragma unroll
    for (int m = 0; m < NB; ++m) {
        float za = fmaxf(h0[m] + b1a, 0.f) * w2a + fmaxf(h1[m] + b1b, 0.f) * w2b;
#pragma unroll
        for (int off = 32; off > 0; off >>= 1) za += __shfl_down(za, off, 64);
        if (lane == 0) {
            int n = base + m;
            if (n < N) s[n] = 1.f / (1.f + __expf(-(za + b2v)));
        }
    }
}

__global__ __launch_bounds__(256) void hist_kernel(const void* __restrict__ ep,
                                                   const int* __restrict__ flag,
                                                   int* __restrict__ cnt, int E) {
    int is64 = (*flag == 0);
    int e = blockIdx.x * blockDim.x + threadIdx.x;
    if (e < E) atomicAdd(&cnt[eload(ep, e, is64)], 1);
}

__global__ __launch_bounds__(256) void bucket_kernel(const int* __restrict__ cnt,
                                                     int* __restrict__ beg,
                                                     int* __restrict__ cursor,
                                                     int* __restrict__ total, int N) {
    int i = blockIdx.x * blockDim.x + threadIdx.x;
    int lane = threadIdx.x & 63;
    int v = (i < N) ? cnt[i] : 0;
    int inc = v;
#pragma unroll
    for (int off = 1; off < 64; off <<= 1) {
        int t = __shfl_up(inc, off, 64);
        if (lane >= off) inc += t;
    }
    int base = 0;
    if (lane == 63) base = atomicAdd(total, inc);
    base = __shfl(base, 63, 64);
    if (i < N) {
        int b = base + inc - v;
        beg[i] = b;
        cursor[i] = b;
    }
}

__global__ __launch_bounds__(256) void scatter32_kernel(const void* __restrict__ ep,
                                                        const int* __restrict__ flag,
                                                        int* __restrict__ cursor,
                                                        int* __restrict__ cols, int E) {
    int is64 = (*flag == 0);
    int e = blockIdx.x * blockDim.x + threadIdx.x;
    if (e < E) {
        int r = eload(ep, e, is64);
        int c = eload(ep, (long long)E + e, is64);
        int p = atomicAdd(&cursor[r], 1);
        cols[p] = c;
    }
}

__global__ __launch_bounds__(256) void agg_f32_kernel(const float4* __restrict__ x4,
                                                      const float* __restrict__ s,
                                                      const int* __restrict__ begs,
                                                      const int* __restrict__ cnt,
                                                      const int* __restrict__ cols,
                                                      float4* __restrict__ out4, int N) {
    int lane = threadIdx.x & 63;
    int node = blockIdx.x * 4 + (threadIdx.x >> 6);
    if (node >= N) return;
    int beg = begs[node], end = beg + cnt[node];
    float4 acc = make_float4(0.f, 0.f, 0.f, 0.f);
    float den = 0.f;
    for (int k = beg; k < end; ++k) {
        int c = cols[k];
        float sc = s[c];
        float4 xv = x4[(size_t)c * 64 + lane];
        acc.x = fmaf(xv.x, sc, acc.x);
        acc.y = fmaf(xv.y, sc, acc.y);
        acc.z = fmaf(xv.z, sc, acc.z);
        acc.w = fmaf(xv.w, sc, acc.w);
        den += sc;
    }
    float4 o = make_float4(0.f, 0.f, 0.f, 0.f);
    if (end > beg) {
        float inv = 1.f / den;
        o.x = acc.x * inv; o.y = acc.y * inv; o.z = acc.z * inv; o.w = acc.w * inv;
    }
    out4[(size_t)node * 64 + lane] = o;
}

// ---------------------------------------------------------------------------
extern "C" void kernel_launch(void* const* d_in, const int* in_sizes, int n_in,
                              void* d_out, int out_size, void* d_ws, size_t ws_size,
                              hipStream_t stream) {
    const float* x  = (const float*)d_in[0];
    const void*  ei = d_in[1];
    const float* W1 = (const float*)d_in[2];
    const float* b1 = (const float*)d_in[3];
    const float* W2 = (const float*)d_in[4];
    const float* b2 = (const float*)d_in[5];
    int N = in_sizes[0] / D;
    int E = in_sizes[1] / 2;

    char* ws = (char*)d_ws;
    int Npad = (N + 63) & ~63;

    // ---- primary layout: flag(16B) | cursor N*pad ints | s N floats |
    //      cols N*cap u16 | Bpack 64KB | xb sliced Npad*D bf16
    auto plan = [&](int cap, int pad, size_t& oCur, size_t& oS, size_t& oCols,
                    size_t& oBp, size_t& oXb) -> size_t {
        oCur  = 16;
        oS    = (oCur + (size_t)N * pad * 4 + 15) & ~15ull;
        oCols = (oS + (size_t)N * 4 + 255) & ~255ull;
        oBp   = (oCols + (size_t)N * cap * 2 + 255) & ~255ull;
        oXb   = (oBp + 65536 + 255) & ~255ull;
        return oXb + (size_t)Npad * D * 2;
    };

    int cap = 64, pad = 16;
    size_t oCur, oS, oCols, oBp, oXb;
    size_t need = plan(cap, pad, oCur, oS, oCols, oBp, oXb);
    if (need > ws_size) { pad = 4;  need = plan(cap, pad, oCur, oS, oCols, oBp, oXb); }
    if (need > ws_size) { pad = 1;  need = plan(cap, pad, oCur, oS, oCols, oBp, oXb); }

    if (N <= 65535 && need <= ws_size) {
        int*            flag   = (int*)(ws);
        int*            cursor = (int*)(ws + oCur);
        float*          s      = (float*)(ws + oS);
        unsigned short* cols   = (unsigned short*)(ws + oCols);
        uint4*          Bpack  = (uint4*)(ws + oBp);
        uint2*          xb     = (uint2*)(ws + oXb);

        // prep: pack W1 (blocks 0-15), flag zero + i64 detect (block 16),
        // cursor zero + cols sentinel fill (blocks 17+)
        const int ZB = 256;
        prep_kernel<<<17 + ZB, 256, 0, stream>>>(W1, Bpack, (const int*)ei, flag, E,
                                                 cursor, cols, cap, N, pad);

        int SB = (N + 63) / 64;                 // score blocks (first)
        int TBe = (E + 2047) / 2048;            // scatter blocks (8 edges/thr)
        score_scatter_kernel<<<SB + TBe, 256, 0, stream>>>(x, Bpack, b1, W2, b2,
                                                           xb, s, ei, flag, cursor,
                                                           cols, cap, pad, Npad,
                                                           N, E, SB);
        int G4 = (N + 3) / 4;
        agg_slice_kernel<<<G4 * 8, 256, 0, stream>>>(xb, s, cols, cap, Npad,
                                                     (float4*)d_out, N);
        return;
    }

    // ---- legacy fp32 fallback (tight CSR) ----
    size_t o0 = 0;
    size_t o1 = 16;
    size_t o2 = (o1 + (size_t)N * 4 + 15) & ~15ull;
    size_t o3 = (o2 + (size_t)N * 4 + 15) & ~15ull;
    size_t o4 = (o3 + (size_t)N * 4 + 15) & ~15ull;
    size_t o5 = (o4 + (size_t)N * 4 + 15) & ~15ull;
    int*   flag   = (int*)(ws + o0);
    int*   total  = (int*)(ws + o0 + 4);
    int*   cnt    = (int*)(ws + o1);
    int*   beg    = (int*)(ws + o2);
    int*   cursor = (int*)(ws + o3);
    float* s      = (float*)(ws + o4);
    int*   cols   = (int*)(ws + o5);

    hipMemsetAsync(ws, 0, o1 + (size_t)N * 4, stream);
    detect_kernel<<<1, 256, 0, stream>>>((const int*)ei, flag, E);
    score_kernel<<<(N + 4 * NB - 1) / (4 * NB), 256, 0, stream>>>(x, W1, b1, W2, b2, s, N);
    hist_kernel<<<(E + 255) / 256, 256, 0, stream>>>(ei, flag, cnt, E);
    bucket_kernel<<<(N + 255) / 256, 256, 0, stream>>>(cnt, beg, cursor, total, N);
    scatter32_kernel<<<(E + 255) / 256, 256, 0, stream>>>(ei, flag, cursor, cols, E);
    agg_f32_kernel<<<(N + 3) / 4, 256, 0, stream>>>((const float4*)x, s, beg, cnt, cols,
                                                    (float4*)d_out, N);
}

// Round 3
// 227.546 us; speedup vs baseline: 1.3126x; 1.3126x over previous
//
#include <hip/hip_runtime.h>
#include <hip/hip_bf16.h>

#define D 256
#define DH 128
#define NB 8   // nodes per wave in fallback score kernel

typedef __attribute__((ext_vector_type(8))) short short8;
typedef __attribute__((ext_vector_type(4))) float floatx4;
typedef __attribute__((ext_vector_type(4))) unsigned int uintx4;

// ---------------------------------------------------------------------------
__device__ __forceinline__ int eload(const void* p, long long i, int is64) {
    if (is64) return (int)((const long long*)p)[i];
    return ((const int*)p)[i];
}

// fp32 bits -> bf16 (RNE), packed pair
__device__ __forceinline__ unsigned pack_bf16(unsigned a, unsigned b) {
    unsigned ra = (a + 0x7fffu + ((a >> 16) & 1u)) >> 16;
    unsigned rb = (b + 0x7fffu + ((b >> 16) & 1u)) & 0xffff0000u;
    return ra | rb;
}

__device__ __forceinline__ float4 unpack_bf16x4(uint2 v) {
    float4 r;
    r.x = __uint_as_float(v.x << 16);
    r.y = __uint_as_float(v.x & 0xffff0000u);
    r.z = __uint_as_float(v.y << 16);
    r.w = __uint_as_float(v.y & 0xffff0000u);
    return r;
}

// ---------------------------------------------------------------------------
// Prep: blocks 0..15 pack W1 into bf16 B-fragment order; block 16 zeroes the
// flag then detects whether edge_index is int64; blocks >= 17 zero the cursor
// array (count-based agg -> no cols sentinel fill needed).
__global__ __launch_bounds__(256) void prep_kernel(const float* __restrict__ W1,
                                                   uint4* __restrict__ Bp,
                                                   const int* __restrict__ ei,
                                                   int* __restrict__ flag, int E,
                                                   int* __restrict__ cursor,
                                                   int N, int pad) {
    if (blockIdx.x >= 17) {
        int stride = (gridDim.x - 17) * 256;
        int tid0 = (blockIdx.x - 17) * 256 + threadIdx.x;
        int total4 = (N * pad) >> 2;
        uint4* c4 = (uint4*)cursor;
        uint4 z = make_uint4(0u, 0u, 0u, 0u);
        for (int i = tid0; i < total4; i += stride) c4[i] = z;
        if (blockIdx.x == 17 && threadIdx.x == 0) {
            for (int i = total4 * 4; i < N * pad; ++i) cursor[i] = 0;
        }
        return;
    }
    if (blockIdx.x == 16) {
        int tid = threadIdx.x;
        if (tid == 0) *flag = 0;
        __syncthreads();
        int limit = min(E, 4096);
        int v = 0;
        for (int i = tid; i < limit; i += 256) v |= ei[2 * i + 1];
#pragma unroll
        for (int off = 32; off > 0; off >>= 1) v |= __shfl_down(v, off, 64);
        if ((tid & 63) == 0) atomicOr(flag, v);
        return;
    }
    int t = blockIdx.x * 256 + threadIdx.x;     // 0..4095
    int lane = t & 63;
    int kt = (t >> 6) & 7;
    int nt = t >> 9;
    int col = nt * 16 + (lane & 15);
    int k0 = kt * 32 + (lane >> 4) * 8;
    unsigned v[8];
#pragma unroll
    for (int j = 0; j < 8; ++j) v[j] = __float_as_uint(W1[(k0 + j) * DH + col]);
    uint4 o;
    o.x = pack_bf16(v[0], v[1]);
    o.y = pack_bf16(v[2], v[3]);
    o.z = pack_bf16(v[4], v[5]);
    o.w = pack_bf16(v[6], v[7]);
    Bp[t] = o;
}

// ---------------------------------------------------------------------------
// FUSED dispatch, NO LDS. Blocks [0, SB): cast x -> xb in XCD-SLICED layout
//   xb[slice][node][slot] (8 slices of 32 dims, 3.2MB/slice -> fits one
//   XCD's 4MB L2 for the agg gather), then per-node MFMA score with
//   A-fragments read back from global xb (same-L2 hits).
// Blocks [SB, ...): edge scatter into u16 buckets (count in cursor).
__global__ __launch_bounds__(256) void score_scatter_kernel(
        const float* __restrict__ x, const uint4* __restrict__ Bp,
        const float* __restrict__ b1, const float* __restrict__ W2,
        const float* __restrict__ b2, uint2* __restrict__ xb,
        float* __restrict__ s,
        const void* __restrict__ ep, const int* __restrict__ flag,
        int* __restrict__ cursor, unsigned short* __restrict__ cols,
        int cap, int pad, int Npad, int N, int E, int SB) {
    if ((int)blockIdx.x >= SB) {
        // ---- scatter part: 8 edges per thread
        int is64 = (*flag == 0);
        int base = (blockIdx.x - SB) * 2048 + threadIdx.x;
        int r[8], c[8];
        bool vld[8];
#pragma unroll
        for (int j = 0; j < 8; ++j) {
            int e = base + j * 256;
            vld[j] = (e < E);
            if (vld[j]) {
                r[j] = eload(ep, e, is64);
                c[j] = eload(ep, (long long)E + e, is64);
            }
        }
#pragma unroll
        for (int j = 0; j < 8; ++j) {
            if (vld[j]) {
                int p = atomicAdd(&cursor[r[j] * pad], 1);
                if (p < cap)
                    __builtin_nontemporal_store((unsigned short)c[j],
                                                &cols[(size_t)r[j] * cap + p]);
            }
        }
        return;
    }

    // ---- score part
    int tid = threadIdx.x;
    int blk = blockIdx.x;
    long long n64 = (long long)N * 64;
    int npad8 = Npad * 8;   // uint2 per slice

    // phase A: coalesced cast of this block's 64 rows into sliced xb
    long long gbase = (long long)blk * 4096 + tid;
#pragma unroll
    for (int i = 0; i < 16; ++i) {
        long long g = gbase + i * 256;
        int idx = i * 256 + tid;
        if (g < n64) {
            uint4 fv = ((const uint4*)x)[g];
            uint2 o;
            o.x = pack_bf16(fv.x, fv.y);
            o.y = pack_bf16(fv.z, fv.w);
            int row = idx >> 6, cc = idx & 63;      // cc = uint2 slot (4 dims)
            int nodeid = blk * 64 + row;
            xb[(size_t)(cc >> 3) * npad8 + (size_t)nodeid * 8 + (cc & 7)] = o;
        }
    }
    __syncthreads();   // drains vmcnt -> writes visible in this CU's L2

    // phase B: MFMA score for this wave's 16 rows, A-fragments from global xb
    int lane = tid & 63;
    int wid = tid >> 6;
    int quad = lane >> 4;
    int rbase = blk * 64 + wid * 16;
    int lnode = rbase + (lane & 15);

    short8 afrag[8];
#pragma unroll
    for (int kt = 0; kt < 8; ++kt)
        afrag[kt] = *(const short8*)&xb[(size_t)kt * npad8 + (size_t)lnode * 8 + quad * 2];

    const short8* Bs = (const short8*)Bp;
    float z0 = 0.f, z1 = 0.f, z2 = 0.f, z3 = 0.f;
#pragma unroll
    for (int nt = 0; nt < 8; ++nt) {
        floatx4 acc = {0.f, 0.f, 0.f, 0.f};
#pragma unroll
        for (int kt = 0; kt < 8; ++kt) {
            short8 b = Bs[(nt * 8 + kt) * 64 + lane];
            acc = __builtin_amdgcn_mfma_f32_16x16x32_bf16(afrag[kt], b, acc, 0, 0, 0);
        }
        int col = nt * 16 + (lane & 15);
        float b1c = b1[col], w2c = W2[col];
        z0 += fmaxf(acc[0] + b1c, 0.f) * w2c;
        z1 += fmaxf(acc[1] + b1c, 0.f) * w2c;
        z2 += fmaxf(acc[2] + b1c, 0.f) * w2c;
        z3 += fmaxf(acc[3] + b1c, 0.f) * w2c;
    }

#pragma unroll
    for (int off = 1; off < 16; off <<= 1) {
        z0 += __shfl_xor(z0, off, 64);
        z1 += __shfl_xor(z1, off, 64);
        z2 += __shfl_xor(z2, off, 64);
        z3 += __shfl_xor(z3, off, 64);
    }
    if ((lane & 15) == 0) {
        float b2v = b2[0];
        int r = rbase + quad * 4;
        float zz[4] = {z0, z1, z2, z3};
#pragma unroll
        for (int j = 0; j < 4; ++j)
            if (r + j < N) s[r + j] = 1.f / (1.f + __expf(-(zz[j] + b2v)));
    }
}

// ---------------------------------------------------------------------------
// XCD-sliced aggregation, v2. slice = blockIdx&7 == XCD id -> each XCD's L2
// only gathers its own 3.2MB dim-slice of xb. Work decomposition restored to
// "lane owns dims across all edges": wave = 8 nodes x 8 dim-lanes. Each
// 8-lane group walks its node's edge list (count-based, from cursor); lane
// accumulates 4 dims over ALL edges -> NO cross-lane reduce. den computed
// redundantly per lane (free). 4-edge unroll for memory-level parallelism.
__global__ __launch_bounds__(256) void agg_slice_kernel(
        const uint2* __restrict__ xb, const float* __restrict__ s,
        const int* __restrict__ cursor,
        const unsigned short* __restrict__ cols,
        int cap, int pad, int Npad, float4* __restrict__ out4, int N) {
    int slice = blockIdx.x & 7;
    int group = blockIdx.x >> 3;                 // node group of 32
    int wid  = threadIdx.x >> 6;
    int lane = threadIdx.x & 63;
    int g  = lane >> 3;                          // node sub-group 0..7
    int dl = lane & 7;                           // uint2 slot (4 dims)
    int node = group * 32 + wid * 8 + g;
    bool alive = (node < N);

    int cnt = 0;
    if (alive) cnt = min(cursor[node * pad], cap);
    const unsigned short* mc = cols + (size_t)node * cap;
    const uint2* xbs = xb + (size_t)slice * Npad * 8;

    float4 acc = make_float4(0.f, 0.f, 0.f, 0.f);
    float den = 0.f;
    int k = 0;
    for (; k + 4 <= cnt; k += 4) {
        int c0 = mc[k], c1 = mc[k + 1], c2 = mc[k + 2], c3 = mc[k + 3];
        float s0 = s[c0], s1 = s[c1], s2 = s[c2], s3 = s[c3];
        uint2 v0 = xbs[(size_t)c0 * 8 + dl];
        uint2 v1 = xbs[(size_t)c1 * 8 + dl];
        uint2 v2 = xbs[(size_t)c2 * 8 + dl];
        uint2 v3 = xbs[(size_t)c3 * 8 + dl];
        float4 f0 = unpack_bf16x4(v0);
        float4 f1 = unpack_bf16x4(v1);
        float4 f2 = unpack_bf16x4(v2);
        float4 f3 = unpack_bf16x4(v3);
        acc.x = fmaf(f0.x, s0, fmaf(f1.x, s1, fmaf(f2.x, s2, fmaf(f3.x, s3, acc.x))));
        acc.y = fmaf(f0.y, s0, fmaf(f1.y, s1, fmaf(f2.y, s2, fmaf(f3.y, s3, acc.y))));
        acc.z = fmaf(f0.z, s0, fmaf(f1.z, s1, fmaf(f2.z, s2, fmaf(f3.z, s3, acc.z))));
        acc.w = fmaf(f0.w, s0, fmaf(f1.w, s1, fmaf(f2.w, s2, fmaf(f3.w, s3, acc.w))));
        den += (s0 + s1) + (s2 + s3);
    }
    for (; k < cnt; ++k) {
        int c0 = mc[k];
        float s0 = s[c0];
        float4 f0 = unpack_bf16x4(xbs[(size_t)c0 * 8 + dl]);
        acc.x = fmaf(f0.x, s0, acc.x);
        acc.y = fmaf(f0.y, s0, acc.y);
        acc.z = fmaf(f0.z, s0, acc.z);
        acc.w = fmaf(f0.w, s0, acc.w);
        den += s0;
    }
    if (alive) {
        floatx4 o = {0.f, 0.f, 0.f, 0.f};
        if (cnt > 0) {
            float inv = 1.f / den;
            o.x = acc.x * inv; o.y = acc.y * inv;
            o.z = acc.z * inv; o.w = acc.w * inv;
        }
        __builtin_nontemporal_store(
            o, (floatx4*)&out4[(size_t)node * 64 + slice * 8 + dl]);
    }
}

// ---------------------------------------------------------------------------
// ------- legacy fp32 fallback path (only if workspace is tiny) -------------
__global__ __launch_bounds__(256) void detect_kernel(const int* __restrict__ ei,
                                                     int* __restrict__ flag, int E) {
    int tid = threadIdx.x;
    int limit = min(E, 4096);
    int v = 0;
    for (int i = tid; i < limit; i += 256) v |= ei[2 * i + 1];
#pragma unroll
    for (int off = 32; off > 0; off >>= 1) v |= __shfl_down(v, off, 64);
    if ((tid & 63) == 0) atomicOr(flag, v);
}

__global__ __launch_bounds__(256) void score_kernel(const float* __restrict__ x,
                                                    const float* __restrict__ W1,
                                                    const float* __restrict__ b1,
                                                    const float* __restrict__ W2,
                                                    const float* __restrict__ b2,
                                                    float* __restrict__ s, int N) {
    __shared__ __align__(16) float xs[4][NB][D];
    int lane = threadIdx.x & 63;
    int wid  = threadIdx.x >> 6;
    int base = (blockIdx.x * 4 + wid) * NB;
#pragma unroll
    for (int m = 0; m < NB; ++m) {
        int n = base + m;
        float4 v = make_float4(0.f, 0.f, 0.f, 0.f);
        if (n < N) v = ((const float4*)x)[(size_t)n * 64 + lane];
        ((float4*)&xs[wid][m][0])[lane] = v;
    }
    __syncthreads();
    float h0[NB], h1[NB];
#pragma unroll
    for (int m = 0; m < NB; ++m) { h0[m] = 0.f; h1[m] = 0.f; }
#pragma unroll 4
    for (int k = 0; k < D; ++k) {
        float w1a = W1[k * DH + lane];
        float w1b = W1[k * DH + 64 + lane];
#pragma unroll
        for (int m = 0; m < NB; ++m) {
            float xv = xs[wid][m][k];
            h0[m] = fmaf(xv, w1a, h0[m]);
            h1[m] = fmaf(xv, w1b, h1[m]);
        }
    }
    float b1a = b1[lane], b1b = b1[lane + 64];
    float w2a = W2[lane], w2b = W2[lane + 64];
    float b2v = b2[0];
#pragma unroll
    for (int m = 0; m < NB; ++m) {
        float za = fmaxf(h0[m] + b1a, 0.f) * w2a + fmaxf(h1[m] + b1b, 0.f) * w2b;
#pragma unroll
        for (int off = 32; off > 0; off >>= 1) za += __shfl_down(za, off, 64);
        if (lane == 0) {
            int n = base + m;
            if (n < N) s[n] = 1.f / (1.f + __expf(-(za + b2v)));
        }
    }
}

__global__ __launch_bounds__(256) void hist_kernel(const void* __restrict__ ep,
                                                   const int* __restrict__ flag,
                                                   int* __restrict__ cnt, int E) {
    int is64 = (*flag == 0);
    int e = blockIdx.x * blockDim.x + threadIdx.x;
    if (e < E) atomicAdd(&cnt[eload(ep, e, is64)], 1);
}

__global__ __launch_bounds__(256) void bucket_kernel(const int* __restrict__ cnt,
                                                     int* __restrict__ beg,
                                                     int* __restrict__ cursor,
                                                     int* __restrict__ total, int N) {
    int i = blockIdx.x * blockDim.x + threadIdx.x;
    int lane = threadIdx.x & 63;
    int v = (i < N) ? cnt[i] : 0;
    int inc = v;
#pragma unroll
    for (int off = 1; off < 64; off <<= 1) {
        int t = __shfl_up(inc, off, 64);
        if (lane >= off) inc += t;
    }
    int base = 0;
    if (lane == 63) base = atomicAdd(total, inc);
    base = __shfl(base, 63, 64);
    if (i < N) {
        int b = base + inc - v;
        beg[i] = b;
        cursor[i] = b;
    }
}

__global__ __launch_bounds__(256) void scatter32_kernel(const void* __restrict__ ep,
                                                        const int* __restrict__ flag,
                                                        int* __restrict__ cursor,
                                                        int* __restrict__ cols, int E) {
    int is64 = (*flag == 0);
    int e = blockIdx.x * blockDim.x + threadIdx.x;
    if (e < E) {
        int r = eload(ep, e, is64);
        int c = eload(ep, (long long)E + e, is64);
        int p = atomicAdd(&cursor[r], 1);
        cols[p] = c;
    }
}

__global__ __launch_bounds__(256) void agg_f32_kernel(const float4* __restrict__ x4,
                                                      const float* __restrict__ s,
                                                      const int* __restrict__ begs,
                                                      const int* __restrict__ cnt,
                                                      const int* __restrict__ cols,
                                                      float4* __restrict__ out4, int N) {
    int lane = threadIdx.x & 63;
    int node = blockIdx.x * 4 + (threadIdx.x >> 6);
    if (node >= N) return;
    int beg = begs[node], end = beg + cnt[node];
    float4 acc = make_float4(0.f, 0.f, 0.f, 0.f);
    float den = 0.f;
    for (int k = beg; k < end; ++k) {
        int c = cols[k];
        float sc = s[c];
        float4 xv = x4[(size_t)c * 64 + lane];
        acc.x = fmaf(xv.x, sc, acc.x);
        acc.y = fmaf(xv.y, sc, acc.y);
        acc.z = fmaf(xv.z, sc, acc.z);
        acc.w = fmaf(xv.w, sc, acc.w);
        den += sc;
    }
    float4 o = make_float4(0.f, 0.f, 0.f, 0.f);
    if (end > beg) {
        float inv = 1.f / den;
        o.x = acc.x * inv; o.y = acc.y * inv; o.z = acc.z * inv; o.w = acc.w * inv;
    }
    out4[(size_t)node * 64 + lane] = o;
}

// ---------------------------------------------------------------------------
extern "C" void kernel_launch(void* const* d_in, const int* in_sizes, int n_in,
                              void* d_out, int out_size, void* d_ws, size_t ws_size,
                              hipStream_t stream) {
    const float* x  = (const float*)d_in[0];
    const void*  ei = d_in[1];
    const float* W1 = (const float*)d_in[2];
    const float* b1 = (const float*)d_in[3];
    const float* W2 = (const float*)d_in[4];
    const float* b2 = (const float*)d_in[5];
    int N = in_sizes[0] / D;
    int E = in_sizes[1] / 2;

    char* ws = (char*)d_ws;
    int Npad = (N + 63) & ~63;

    // ---- primary layout: flag(16B) | cursor N*pad ints | s N floats |
    //      cols N*cap u16 | Bpack 64KB | xb sliced Npad*D bf16
    auto plan = [&](int cap, int pad, size_t& oCur, size_t& oS, size_t& oCols,
                    size_t& oBp, size_t& oXb) -> size_t {
        oCur  = 16;
        oS    = (oCur + (size_t)N * pad * 4 + 15) & ~15ull;
        oCols = (oS + (size_t)N * 4 + 255) & ~255ull;
        oBp   = (oCols + (size_t)N * cap * 2 + 255) & ~255ull;
        oXb   = (oBp + 65536 + 255) & ~255ull;
        return oXb + (size_t)Npad * D * 2;
    };

    int cap = 64, pad = 16;
    size_t oCur, oS, oCols, oBp, oXb;
    size_t need = plan(cap, pad, oCur, oS, oCols, oBp, oXb);
    if (need > ws_size) { pad = 4;  need = plan(cap, pad, oCur, oS, oCols, oBp, oXb); }
    if (need > ws_size) { pad = 1;  need = plan(cap, pad, oCur, oS, oCols, oBp, oXb); }

    if (N <= 65535 && need <= ws_size) {
        int*            flag   = (int*)(ws);
        int*            cursor = (int*)(ws + oCur);
        float*          s      = (float*)(ws + oS);
        unsigned short* cols   = (unsigned short*)(ws + oCols);
        uint4*          Bpack  = (uint4*)(ws + oBp);
        uint2*          xb     = (uint2*)(ws + oXb);

        // prep: pack W1 (blocks 0-15), flag zero + i64 detect (block 16),
        // cursor zero (blocks 17+)
        const int ZB = 128;
        prep_kernel<<<17 + ZB, 256, 0, stream>>>(W1, Bpack, (const int*)ei, flag, E,
                                                 cursor, N, pad);

        int SB = (N + 63) / 64;                 // score blocks (first)
        int TBe = (E + 2047) / 2048;            // scatter blocks (8 edges/thr)
        score_scatter_kernel<<<SB + TBe, 256, 0, stream>>>(x, Bpack, b1, W2, b2,
                                                           xb, s, ei, flag, cursor,
                                                           cols, cap, pad, Npad,
                                                           N, E, SB);
        int G32 = (N + 31) / 32;
        agg_slice_kernel<<<G32 * 8, 256, 0, stream>>>(xb, s, cursor, cols, cap, pad,
                                                      Npad, (float4*)d_out, N);
        return;
    }

    // ---- legacy fp32 fallback (tight CSR) ----
    size_t o0 = 0;
    size_t o1 = 16;
    size_t o2 = (o1 + (size_t)N * 4 + 15) & ~15ull;
    size_t o3 = (o2 + (size_t)N * 4 + 15) & ~15ull;
    size_t o4 = (o3 + (size_t)N * 4 + 15) & ~15ull;
    size_t o5 = (o4 + (size_t)N * 4 + 15) & ~15ull;
    int*   flag   = (int*)(ws + o0);
    int*   total  = (int*)(ws + o0 + 4);
    int*   cnt    = (int*)(ws + o1);
    int*   beg    = (int*)(ws + o2);
    int*   cursor = (int*)(ws + o3);
    float* s      = (float*)(ws + o4);
    int*   cols   = (int*)(ws + o5);

    hipMemsetAsync(ws, 0, o1 + (size_t)N * 4, stream);
    detect_kernel<<<1, 256, 0, stream>>>((const int*)ei, flag, E);
    score_kernel<<<(N + 4 * NB - 1) / (4 * NB), 256, 0, stream>>>(x, W1, b1, W2, b2, s, N);
    hist_kernel<<<(E + 255) / 256, 256, 0, stream>>>(ei, flag, cnt, E);
    bucket_kernel<<<(N + 255) / 256, 256, 0, stream>>>(cnt, beg, cursor, total, N);
    scatter32_kernel<<<(E + 255) / 256, 256, 0, stream>>>(ei, flag, cursor, cols, E);
    agg_f32_kernel<<<(N + 3) / 4, 256, 0, stream>>>((const float4*)x, s, beg, cnt, cols,
                                                    (float4*)d_out, N);
}